// Round 1
// baseline (62.525 us; speedup 1.0000x reference)
//
#include <hip/hip_runtime.h>

// YOLOv1 loss on MI355X. Shapes: input/target (4096, 14, 14, 30) f32.
// B=2 boxes, C=20 classes. Output: scalar f32 = total_loss / 4096.
// Memory-bound streaming reduction (~192.7 MB read once).

#define COORD 5.0f
#define NOOBJ 0.5f

#define CPB 256            // cells per block == threads per block
#define THREADS 256
#define FPC 30             // floats per cell
#define TILE_F4 (CPB * FPC / 4)   // 1920 float4 per tensor tile

__global__ __launch_bounds__(THREADS) void yolo_loss_kernel(
    const float* __restrict__ inp,
    const float* __restrict__ tgt,
    float* __restrict__ out,
    float inv_n)
{
    __shared__ float lin[CPB * FPC];   // 30720 B
    __shared__ float ltg[CPB * FPC];   // 30720 B
    __shared__ float wsum[THREADS / 64];

    const int tid = threadIdx.x;
    const size_t base = (size_t)blockIdx.x * (CPB * FPC);

    // ---- coalesced global -> LDS staging (float4) ----
    const float4* gi = (const float4*)(inp + base);
    const float4* gt = (const float4*)(tgt + base);
    float4* li4 = (float4*)lin;
    float4* lt4 = (float4*)ltg;
#pragma unroll
    for (int it = 0; it < 8; ++it) {
        int i = tid + it * THREADS;
        if (i < TILE_F4) {
            li4[i] = gi[i];
            lt4[i] = gt[i];
        }
    }
    __syncthreads();

    // ---- per-cell loss from LDS ----
    const float* ip = &lin[tid * FPC];
    const float* tp = &ltg[tid * FPC];

    float c_p0 = ip[0], c_p1 = ip[1];
    float c_t0 = tp[0], c_t1 = tp[1];

    bool obj0 = (c_t0 == 1.0f);
    bool obj1 = (c_t1 == 1.0f);
    float f0 = obj0 ? 1.0f : 0.0f;                 // first == slot0 if obj0
    float f1 = (obj1 && !obj0) ? 1.0f : 0.0f;      // slot1 only if !obj0
    float hasf = (obj0 || obj1) ? 1.0f : 0.0f;

    float d0 = c_p0 - c_t0;
    float d1 = c_p1 - c_t1;
    float sqc0 = d0 * d0;
    float sqc1 = d1 * d1;

    // box slot 0: floats [2..5], slot 1: floats [6..9]
    float dx0 = ip[2] - tp[2], dy0 = ip[3] - tp[3];
    float xy0 = dx0 * dx0 + dy0 * dy0;
    float dw0 = sqrtf(ip[4]) - sqrtf(tp[4]);
    float dh0 = sqrtf(ip[5]) - sqrtf(tp[5]);
    float wh0 = dw0 * dw0 + dh0 * dh0;

    float dx1 = ip[6] - tp[6], dy1 = ip[7] - tp[7];
    float xy1 = dx1 * dx1 + dy1 * dy1;
    float dw1 = sqrtf(ip[8]) - sqrtf(tp[8]);
    float dh1 = sqrtf(ip[9]) - sqrtf(tp[9]);
    float wh1 = dw1 * dw1 + dh1 * dh1;

    // classes: floats [10..29]
    float cls = 0.0f;
#pragma unroll
    for (int k = 10; k < 30; ++k) {
        float d = ip[k] - tp[k];
        cls = fmaf(d, d, cls);
    }

    float contrib =
        COORD * (f0 * (xy0 + wh0) + f1 * (xy1 + wh1)) +
        (f0 * sqc0 + f1 * sqc1) +
        hasf * cls +
        (1.0f - hasf) * NOOBJ * (sqc0 + sqc1);

    // ---- wave reduce (64 lanes) ----
#pragma unroll
    for (int off = 32; off > 0; off >>= 1)
        contrib += __shfl_down(contrib, off, 64);

    const int wid = tid >> 6;
    const int lane = tid & 63;
    if (lane == 0) wsum[wid] = contrib;
    __syncthreads();

    if (tid == 0) {
        float s = wsum[0] + wsum[1] + wsum[2] + wsum[3];
        atomicAdd(out, s * inv_n);
    }
}

extern "C" void kernel_launch(void* const* d_in, const int* in_sizes, int n_in,
                              void* d_out, int out_size, void* d_ws, size_t ws_size,
                              hipStream_t stream) {
    const float* inp = (const float*)d_in[0];
    const float* tgt = (const float*)d_in[1];
    float* out = (float*)d_out;

    const int total_cells = 4096 * 14 * 14;        // 802816
    const int grid = total_cells / CPB;            // 3136 exactly

    hipMemsetAsync(out, 0, sizeof(float), stream);
    yolo_loss_kernel<<<grid, THREADS, 0, stream>>>(inp, tgt, out, 1.0f / 4096.0f);
}